// Round 7
// baseline (192.729 us; speedup 1.0000x reference)
//
#include <hip/hip_runtime.h>
#include <hip/hip_bf16.h>

#define NDIM  64
#define BP    72                 // bf16 LDS pitch: 144 B rows -> b128 frag reads conflict-benign
#define SLICE (NDIM * BP)        // 4608 bf16 per buffer (9216 B)
#define DT_   0.01f

typedef __attribute__((ext_vector_type(8)))  short bf16x8;
typedef __attribute__((ext_vector_type(16))) float f32x16;

// full-matrix fragment set: f[rb][j] -> lane(ln,hq) holds M[32*rb+ln][16*j+8*hq+0..7]
struct OpF { bf16x8 f[2][4]; };

// ---------------- bf16 helpers ----------------

__device__ __forceinline__ unsigned short f2b(float x) {
    __hip_bfloat16 h = __float2bfloat16(x);          // RTNE
    return __builtin_bit_cast(unsigned short, h);
}
__device__ __forceinline__ float b2f(unsigned short u) {
    unsigned int v = (unsigned int)u << 16;
    return __builtin_bit_cast(float, v);
}
__device__ __forceinline__ unsigned int f2b2(float lo, float hi) {
    return (unsigned int)f2b(lo) | ((unsigned int)f2b(hi) << 16);
}

// ---------------- fragment loads ----------------

__device__ __forceinline__ void ld_ws_op(OpF& F, const unsigned short* __restrict__ p,
                                         int ln, int hq) {
#pragma unroll
    for (int rb = 0; rb < 2; ++rb)
#pragma unroll
        for (int j = 0; j < 4; ++j)
            F.f[rb][j] = *(const bf16x8*)&p[(32 * rb + ln) * 64 + j * 16 + hq * 8];
}

__device__ __forceinline__ void ld_rho(OpF& F, const float* __restrict__ p, int ln, int hq) {
#pragma unroll
    for (int rb = 0; rb < 2; ++rb)
#pragma unroll
        for (int j = 0; j < 4; ++j) {
            const float* q = &p[(32 * rb + ln) * 64 + j * 16 + hq * 8];
            float4 u = *(const float4*)q;
            float4 v = *(const float4*)(q + 4);
            uint4 o;
            o.x = f2b2(u.x, u.y); o.y = f2b2(u.z, u.w);
            o.z = f2b2(v.x, v.y); o.w = f2b2(v.z, v.w);
            F.f[rb][j] = __builtin_bit_cast(bf16x8, o);
        }
}

__device__ __forceinline__ bf16x8 lfrag(const unsigned short* buf, int rb, int j, int ln, int hq) {
    return *(const bf16x8*)&buf[(32 * rb + ln) * BP + j * 16 + hq * 8];
}

__device__ __forceinline__ void ld_lds_op(OpF& F, const unsigned short* buf, int ln, int hq) {
#pragma unroll
    for (int rb = 0; rb < 2; ++rb)
#pragma unroll
        for (int j = 0; j < 4; ++j)
            F.f[rb][j] = lfrag(buf, rb, j, ln, hq);
}

// ---------------- full-matrix NT gemms (C = A @ B^T), 16 MFMA ----------------

template <bool ACC>
__device__ __forceinline__ void gemmR(f32x16 (&C)[2][2], const OpF& A, const OpF& B) {
    if (!ACC) {
#pragma unroll
        for (int qr = 0; qr < 2; ++qr)
#pragma unroll
            for (int qc = 0; qc < 2; ++qc)
#pragma unroll
                for (int r = 0; r < 16; ++r) C[qr][qc][r] = 0.f;
    }
#pragma unroll
    for (int j = 0; j < 4; ++j)
#pragma unroll
        for (int qr = 0; qr < 2; ++qr)
#pragma unroll
            for (int qc = 0; qc < 2; ++qc)
                C[qr][qc] = __builtin_amdgcn_mfma_f32_32x32x16_bf16(
                    A.f[qr][j], B.f[qc][j], C[qr][qc], 0, 0, 0);
}

template <bool ACC>
__device__ __forceinline__ void gemmL(f32x16 (&C)[2][2], const unsigned short* buf,
                                      const OpF& B, int ln, int hq) {
    if (!ACC) {
#pragma unroll
        for (int qr = 0; qr < 2; ++qr)
#pragma unroll
            for (int qc = 0; qc < 2; ++qc)
#pragma unroll
                for (int r = 0; r < 16; ++r) C[qr][qc][r] = 0.f;
    }
#pragma unroll
    for (int j = 0; j < 4; ++j) {
        bf16x8 a0 = lfrag(buf, 0, j, ln, hq);
        bf16x8 a1 = lfrag(buf, 1, j, ln, hq);
        C[0][0] = __builtin_amdgcn_mfma_f32_32x32x16_bf16(a0, B.f[0][j], C[0][0], 0, 0, 0);
        C[0][1] = __builtin_amdgcn_mfma_f32_32x32x16_bf16(a0, B.f[1][j], C[0][1], 0, 0, 0);
        C[1][0] = __builtin_amdgcn_mfma_f32_32x32x16_bf16(a1, B.f[0][j], C[1][0], 0, 0, 0);
        C[1][1] = __builtin_amdgcn_mfma_f32_32x32x16_bf16(a1, B.f[1][j], C[1][1], 0, 0, 0);
    }
}

// transposed store of full slot set: result R -> buffer holds R^T row-major (b64 writes)
__device__ __forceinline__ void stTF(unsigned short* buf, const f32x16 (&C)[2][2],
                                     int ln, int hq) {
#pragma unroll
    for (int qc = 0; qc < 2; ++qc)
#pragma unroll
        for (int qr = 0; qr < 2; ++qr)
#pragma unroll
            for (int g = 0; g < 4; ++g) {
                uint2 o;
                o.x = f2b2(C[qr][qc][4 * g + 0], C[qr][qc][4 * g + 1]);
                o.y = f2b2(C[qr][qc][4 * g + 2], C[qr][qc][4 * g + 3]);
                *(uint2*)&buf[(32 * qc + ln) * BP + 32 * qr + 8 * g + 4 * hq] = o;
            }
}

// ---------------- frag-space linear combos (frag = fixed element permutation) ----------------

__device__ __forceinline__ bf16x8 comb2(bf16x8 a, bf16x8 b, float cb) {
    bf16x8 r;
#pragma unroll
    for (int e = 0; e < 8; e += 2) {
        float f0 = b2f((unsigned short)a[e])     + cb * b2f((unsigned short)b[e]);
        float f1 = b2f((unsigned short)a[e + 1]) + cb * b2f((unsigned short)b[e + 1]);
        unsigned int pk = f2b2(f0, f1);
        r[e]     = (short)(pk & 0xffffu);
        r[e + 1] = (short)(pk >> 16);
    }
    return r;
}
__device__ __forceinline__ bf16x8 comb3(bf16x8 a, bf16x8 b, bf16x8 c, float cb, float cc) {
    bf16x8 r;
#pragma unroll
    for (int e = 0; e < 8; e += 2) {
        float f0 = b2f((unsigned short)a[e]) + cb * b2f((unsigned short)b[e])
                 + cc * b2f((unsigned short)c[e]);
        float f1 = b2f((unsigned short)a[e + 1]) + cb * b2f((unsigned short)b[e + 1])
                 + cc * b2f((unsigned short)c[e + 1]);
        unsigned int pk = f2b2(f0, f1);
        r[e]     = (short)(pk & 0xffffu);
        r[e + 1] = (short)(pk >> 16);
    }
    return r;
}
__device__ __forceinline__ void opComb2(OpF& R, const OpF& A, const OpF& B, float cb) {
#pragma unroll
    for (int rb = 0; rb < 2; ++rb)
#pragma unroll
        for (int j = 0; j < 4; ++j) R.f[rb][j] = comb2(A.f[rb][j], B.f[rb][j], cb);
}
__device__ __forceinline__ void opComb3(OpF& R, const OpF& A, const OpF& B, const OpF& Cc,
                                        float cb, float cc) {
#pragma unroll
    for (int rb = 0; rb < 2; ++rb)
#pragma unroll
        for (int j = 0; j < 4; ++j) R.f[rb][j] = comb3(A.f[rb][j], B.f[rb][j], Cc.f[rb][j], cb, cc);
}

// ---------------- setup: 11 blocks ----------------
// ws (bf16, 4096 each): 0=Uh 1=U1 2=L00 3=L01 4=Lh0 5=Lh1 6=L10 7=L11 8=V 9=c16*L10 10=c16*L11

__global__ void __launch_bounds__(256) krk_setup(const float* __restrict__ Uh,
                                                 const float* __restrict__ U1,
                                                 const float* __restrict__ L0,
                                                 const float* __restrict__ Lh,
                                                 const float* __restrict__ L1,
                                                 unsigned short* __restrict__ ws) {
    __shared__ unsigned short sW [NDIM * BP];
    __shared__ unsigned short sWt[NDIM * BP];

    const int blk = blockIdx.x, tid = threadIdx.x;
    const float c16 = DT_ / 6.f;

    if (blk < 8) {
        const float* srcs[8] = {Uh, U1, L0, L0 + 4096, Lh, Lh + 4096, L1, L1 + 4096};
        const float* s = srcs[blk];
        unsigned short* d = ws + blk * 4096;
#pragma unroll
        for (int i = 0; i < 4; ++i) {
            int flat = (tid + i * 256) * 4;
            float4 v = *(const float4*)&s[flat];
            uint2 o; o.x = f2b2(v.x, v.y); o.y = f2b2(v.z, v.w);
            *(uint2*)&d[flat] = o;
        }
        return;
    }
    if (blk >= 9) {                                  // scaled L1 copies
        const float* s = (blk == 9) ? L1 : L1 + 4096;
        unsigned short* d = ws + blk * 4096;
#pragma unroll
        for (int i = 0; i < 4; ++i) {
            int flat = (tid + i * 256) * 4;
            float4 v = *(const float4*)&s[flat];
            uint2 o; o.x = f2b2(c16 * v.x, c16 * v.y); o.y = f2b2(c16 * v.z, c16 * v.w);
            *(uint2*)&d[flat] = o;
        }
        return;
    }

    // ---- block 8: V = I + W + W^2  (W = I - Uh), row-major bf16
    const int lane = tid & 63, w = tid >> 6, ln = lane & 31, hq = lane >> 5;
    const int rw = 32 * (w >> 1), cw = 32 * (w & 1);

#pragma unroll
    for (int i = 0; i < 4; ++i) {
        int flat = (tid + i * 256) * 4;
        int r = flat >> 6, c = flat & 63;
        float4 u = *(const float4*)&Uh[flat];
        float wv[4] = {-u.x, -u.y, -u.z, -u.w};
#pragma unroll
        for (int j = 0; j < 4; ++j)
            if (r == c + j) wv[j] += 1.f;
        unsigned short o[4] = {f2b(wv[0]), f2b(wv[1]), f2b(wv[2]), f2b(wv[3])};
        *(uint2*)&sW[r * BP + c] = *(uint2*)o;
#pragma unroll
        for (int j = 0; j < 4; ++j) sWt[(c + j) * BP + r] = o[j];
    }
    OpF Fw;                                          // W row-frags (rows cw+ln)
    {
        const int n = cw + ln;
#pragma unroll
        for (int j = 0; j < 4; ++j) {
            const int k0 = j * 16 + hq * 8;
            const float* q = &Uh[n * 64 + k0];
            float4 u = *(const float4*)q;
            float4 v = *(const float4*)(q + 4);
            float wv[8] = {-u.x, -u.y, -u.z, -u.w, -v.x, -v.y, -v.z, -v.w};
#pragma unroll
            for (int e = 0; e < 8; ++e)
                if (n == k0 + e) wv[e] += 1.f;
            uint4 o;
            o.x = f2b2(wv[0], wv[1]); o.y = f2b2(wv[2], wv[3]);
            o.z = f2b2(wv[4], wv[5]); o.w = f2b2(wv[6], wv[7]);
            Fw.f[0][j] = __builtin_bit_cast(bf16x8, o);
        }
    }
    __syncthreads();

    f32x16 t0;
#pragma unroll
    for (int r = 0; r < 16; ++r) t0[r] = 0.f;
#pragma unroll
    for (int j = 0; j < 4; ++j)
        t0 = __builtin_amdgcn_mfma_f32_32x32x16_bf16(
            *(const bf16x8*)&sWt[(rw + ln) * BP + j * 16 + hq * 8], Fw.f[0][j], t0, 0, 0, 0);
    // t0 = (W^2)^T slots; W^T slots via transposed read of sW
    float wts[16];
#pragma unroll
    for (int g = 0; g < 4; ++g) {
        uint2 u = *(const uint2*)&sW[(cw + ln) * BP + rw + 8 * g + 4 * hq];
        unsigned short o[4]; *(uint2*)o = u;
#pragma unroll
        for (int j = 0; j < 4; ++j) wts[4 * g + j] = b2f(o[j]);
    }
    unsigned short* ws8 = ws + 8 * 4096;
#pragma unroll
    for (int g = 0; g < 4; ++g) {
        uint2 o;
#pragma unroll
        for (int j = 0; j < 4; j += 2) {
            int r0 = 4 * g + j, r1 = r0 + 1;
            int row0 = rw + (r0 & 3) + 8 * g + 4 * hq;
            float v0 = ((row0 == cw + ln) ? 1.f : 0.f) + wts[r0] + t0[r0];
            float v1 = ((row0 + 1 == cw + ln) ? 1.f : 0.f) + wts[r1] + t0[r1];
            if (j == 0) o.x = f2b2(v0, v1); else o.y = f2b2(v0, v1);
        }
        *(uint2*)&ws8[(cw + ln) * 64 + rw + 8 * g + 4 * hq] = o;   // V row-major
    }
}

// ---------------- main: one WAVE per density matrix, zero barriers ----------------
// S0 = sum L0k p L0k^T ; rho1 = Uh(p+c12 S0)Uh^T ; S1 = sum Lhk rho1 Lhk^T ; H1 = V S1 V^T
// M1 = p + c16 S0 + c23 H1 ; M2 = p + DT H1 ; rho2 = U1 M2 U1^T ;
// out = U1 M1 U1^T + sum (c16 L1k) rho2 L1k^T.

__global__ void __launch_bounds__(128, 2) krk_main(const float* __restrict__ rho0,
                                                   const unsigned short* __restrict__ ws,
                                                   float* __restrict__ out) {
    __shared__ unsigned short L[2 * 2 * SLICE];      // 2 waves x 2 private slices = 36864 B

    const int tid = threadIdx.x;
    const int wv = tid >> 6, lane = tid & 63, ln = lane & 31, hq = lane >> 5;
    unsigned short* bufA = &L[(2 * wv + 0) * SLICE];
    unsigned short* bufB = &L[(2 * wv + 1) * SLICE];
    const int mat = blockIdx.x * 2 + wv;
    const float* rho = rho0 + (size_t)mat * (NDIM * NDIM);

    const float c12 = 0.5f * DT_, c16 = DT_ / 6.f, c23 = 2.f * DT_ / 3.f;

    OpF Rf, S0f, H1f, Oa, Ob, Tf;
    f32x16 C[2][2];

    ld_rho(Rf, rho, ln, hq);                         // rho0 frags straight from global
    ld_ws_op(Oa, ws + 2 * 4096, ln, hq);             // L00
    ld_ws_op(Ob, ws + 3 * 4096, ln, hq);             // L01

    // ---- S0
    gemmR<false>(C, Rf, Oa); stTF(bufA, C, ln, hq);  // bufA = (p L00^T)^T = L00 p
    gemmR<false>(C, Rf, Ob); stTF(bufB, C, ln, hq);  // bufB = L01 p
    gemmL<false>(C, bufA, Oa, ln, hq);
    gemmL<true >(C, bufB, Ob, ln, hq);               // C = S0 slots
    stTF(bufA, C, ln, hq);                           // bufA = S0 (symmetric)
    ld_lds_op(S0f, bufA, ln, hq);                    // S0 frags (persistent)

    // ---- rho1 = Uh (p + c12 S0) Uh^T
    opComb2(Tf, Rf, S0f, c12);                       // Tf = X frags
    ld_ws_op(Oa, ws + 0 * 4096, ln, hq);             // Uh
    gemmR<false>(C, Tf, Oa); stTF(bufA, C, ln, hq);  // bufA = Uh X
    gemmL<false>(C, bufA, Oa, ln, hq);               // C = rho1 slots
    stTF(bufB, C, ln, hq);                           // bufB = rho1 (symmetric)

    // ---- S1
    ld_ws_op(Oa, ws + 4 * 4096, ln, hq);             // Lh0
    ld_ws_op(Ob, ws + 5 * 4096, ln, hq);             // Lh1
    gemmL<false>(C, bufB, Oa, ln, hq); stTF(bufA, C, ln, hq);   // bufA = Lh0 rho1
    gemmL<false>(C, bufB, Ob, ln, hq); stTF(bufB, C, ln, hq);   // bufB = Lh1 rho1 (reads precede writes)
    gemmL<false>(C, bufA, Oa, ln, hq);
    gemmL<true >(C, bufB, Ob, ln, hq);               // C = S1 slots
    stTF(bufA, C, ln, hq);                           // bufA = S1 (symmetric)

    // ---- H1 = V S1 V^T
    ld_ws_op(Oa, ws + 8 * 4096, ln, hq);             // V
    gemmL<false>(C, bufA, Oa, ln, hq); stTF(bufB, C, ln, hq);   // bufB = V S1
    gemmL<false>(C, bufB, Oa, ln, hq);               // C = H1 slots
    stTF(bufA, C, ln, hq);                           // bufA = H1 (symmetric)
    ld_lds_op(H1f, bufA, ln, hq);

    // ---- M1, M2 in frag space
    OpF M1f, M2f;
    opComb3(M1f, Rf, S0f, H1f, c16, c23);            // M1 = p + c16 S0 + c23 H1
    opComb2(M2f, Rf, H1f, DT_);                      // M2 = p + DT H1
    ld_ws_op(Oa, ws + 1 * 4096, ln, hq);             // U1
    gemmR<false>(C, M1f, Oa); stTF(bufA, C, ln, hq); // bufA = U1 M1
    gemmR<false>(C, M2f, Oa); stTF(bufB, C, ln, hq); // bufB = U1 M2
    gemmL<false>(C, bufB, Oa, ln, hq);               // C = rho2 slots
    stTF(bufB, C, ln, hq);                           // bufB = rho2 (symmetric)

    // ---- out = U1 M1 U1^T + sum (c16 L1k) rho2 L1k^T
    f32x16 O[2][2];
    gemmL<false>(O, bufA, Oa, ln, hq);               // O = a1 slots ; bufA free
    ld_ws_op(Oa, ws + 6 * 4096, ln, hq);             // L10
    ld_ws_op(Ob, ws + 7 * 4096, ln, hq);             // L11
    gemmL<false>(C, bufB, Oa, ln, hq); stTF(bufA, C, ln, hq);   // bufA = L10 rho2
    gemmL<false>(C, bufB, Ob, ln, hq); stTF(bufB, C, ln, hq);   // bufB = L11 rho2
    ld_ws_op(Oa, ws + 9 * 4096, ln, hq);             // c16*L10
    ld_ws_op(Ob, ws + 10 * 4096, ln, hq);            // c16*L11
    gemmL<true>(O, bufA, Oa, ln, hq);                // O += (L10 rho2)@(c16 L10)^T
    gemmL<true>(O, bufB, Ob, ln, hq);                // O += (L11 rho2)@(c16 L11)^T

    // out symmetric -> transposed store is exact; float4, coalesced within wave
    float* o = out + (size_t)mat * (NDIM * NDIM);
#pragma unroll
    for (int qc = 0; qc < 2; ++qc)
#pragma unroll
        for (int qr = 0; qr < 2; ++qr)
#pragma unroll
            for (int g = 0; g < 4; ++g) {
                float4 v;
                v.x = O[qr][qc][4 * g + 0];
                v.y = O[qr][qc][4 * g + 1];
                v.z = O[qr][qc][4 * g + 2];
                v.w = O[qr][qc][4 * g + 3];
                *(float4*)&o[(32 * qc + ln) * 64 + 32 * qr + 8 * g + 4 * hq] = v;
            }
}

// ---------------- host launch ----------------

extern "C" void kernel_launch(void* const* d_in, const int* in_sizes, int n_in,
                              void* d_out, int out_size, void* d_ws, size_t ws_size,
                              hipStream_t stream) {
    const float* rho0 = (const float*)d_in[0];
    const float* Uh   = (const float*)d_in[1];
    const float* U1   = (const float*)d_in[2];
    const float* L0   = (const float*)d_in[3];
    const float* Lh   = (const float*)d_in[4];
    const float* L1   = (const float*)d_in[5];
    float* out = (float*)d_out;
    unsigned short* ws = (unsigned short*)d_ws;      // 11 bf16 64x64 matrices = 90112 B

    int Bn = in_sizes[0] / (NDIM * NDIM);            // 4096

    krk_setup<<<11, 256, 0, stream>>>(Uh, U1, L0, Lh, L1, ws);
    krk_main<<<Bn / 2, 128, 0, stream>>>(rho0, ws, out);
}